// Round 1
// baseline (323.312 us; speedup 1.0000x reference)
//
#include <hip/hip_runtime.h>

#define H 192
#define W 192
#define CIN 32
#define NOUT 32
#define NB 16
#define PADI 4

#define HT 32          // output rows per block
#define WTL 16         // output cols per block
#define RROWS 40       // HT + 8 halo
#define RCOLS 24       // WTL + 8 halo
#define CP 40          // channel stride in LDS (padded 32->40: 80B = 20 dwords, 2-way banks, 16B aligned)

typedef __attribute__((ext_vector_type(8))) short bf16x8;
typedef __attribute__((ext_vector_type(4))) float f32x4;

__device__ __forceinline__ unsigned short f2bf(float f) {
    union { float f; unsigned int u; } v; v.f = f;
    unsigned int r = v.u + 0x7fffu + ((v.u >> 16) & 1u);
    return (unsigned short)(r >> 16);
}

// ---- Gaussian kernel generation: one thread per (o, i) pair ----
// Output layout (bf16 as ushort): W2g[mt][tap][quad][m][j]  (mt=o>>4, m=o&15, quad=i>>3, j=i&7)
// so that conv-kernel lane l reads A[m=l&15][k=8*(l>>4)+j] as one contiguous 16B vector.
__global__ void genw_kernel(const float* __restrict__ wp, unsigned short* __restrict__ W2g) {
    int idx = blockIdx.x * blockDim.x + threadIdx.x;
    if (idx >= NOUT * CIN) return;
    int o = idx / CIN;
    float sx = wp[idx * 3 + 0], sy = wp[idx * 3 + 1], th = wp[idx * 3 + 2];
    float rad = th / 180.0f * 3.14159265358979323846f;
    float co = cosf(rad), si = sinf(rad);
    float sx2 = sx * sx, sy2 = sy * sy;
    float a = co * co * sx2 + si * si * sy2;
    float b = co * si * (sx2 - sy2);
    float d = si * si * sx2 + co * co * sy2;
    float det = a * d - b * b;
    float ia = d / det, ib = -b / det, idd = a / det;
    float ker[81];
    float sum = 0.0f;
    for (int ky = 0; ky < 9; ky++) {
        float yy = (float)(ky - 4);
        for (int kx = 0; kx < 9; kx++) {
            float xx = (float)(kx - 4);
            float q = ia * xx * xx + 2.0f * ib * xx * yy + idd * yy * yy;
            float v = expf(-0.5f * q);
            ker[ky * 9 + kx] = v;
            sum += v;
        }
    }
    float inv = 1.0f / sum;
    int i = idx % CIN;
    int mt = o >> 4, m = o & 15, quad = i >> 3, j = i & 7;
    for (int tap = 0; tap < 81; tap++) {
        W2g[((((mt * 81 + tap) * 4 + quad) * 16 + m) << 3) + j] = f2bf(ker[tap] * inv);
    }
}

// ---- Conv kernel: implicit GEMM, M=32 och, N=pixels, K=tap*32+ch ----
// Block: 256 thr = 4 waves. Block tile: 32 rows x 16 cols, all 32 och.
// Wave v owns 8 output rows [v*8, v*8+8), 16 cols.
// dx-outer loop: one B-frag (lds row r', col shift dx, 8ch) feeds up to 9 dy x 2 mt MFMAs.
__global__ __launch_bounds__(256, 2) void conv_kernel(
    const float* __restrict__ x, const unsigned short* __restrict__ W2g,
    const float* __restrict__ bias, float* __restrict__ out)
{
    __shared__ __align__(16) unsigned short ldsx[RROWS * RCOLS * CP];  // 76,800 B

    const int t = threadIdx.x;
    const int bid = blockIdx.x;
    const int wb = bid % (W / WTL);                 // 0..11
    const int hb = (bid / (W / WTL)) % (H / HT);    // 0..5
    const int n  = bid / ((W / WTL) * (H / HT));    // 0..15
    const int row0 = hb * HT - PADI;
    const int col0 = wb * WTL - PADI;
    const float* xn = x + (size_t)n * CIN * H * W;

    // ---- stage x tile -> LDS bf16, layout [r][w][c] (c contiguous, stride CP) ----
    // lanes: w8 = l&7 (8 consecutive cols, 32B runs), c = l>>3 -> conflict-free b16 writes
    for (int it = 0; it < (RROWS * RCOLS * CIN) / 256; ++it) {   // 120 iters
        int idx = it * 256 + t;
        int w8 = idx & 7;
        int c  = (idx >> 3) & 31;
        int rest = idx >> 8;            // == it
        int wblk = rest % 3;
        int r = rest / 3;               // 0..39
        int w = wblk * 8 + w8;          // 0..23
        int row = row0 + r, col = col0 + w;
        float v = 0.0f;
        if ((unsigned)row < (unsigned)H && (unsigned)col < (unsigned)W)
            v = xn[(c * H + row) * W + col];
        ldsx[(r * RCOLS + w) * CP + c] = f2bf(v);
    }
    __syncthreads();

    const int wave = t >> 6;
    const int lane = t & 63;
    const int l15 = lane & 15;      // A: m-row / B: pixel col / D: col
    const int quad = lane >> 4;     // A/B: k-group (8 ch) / D: och-quad

    f32x4 acc[8][2];
    #pragma unroll
    for (int i = 0; i < 8; i++) {
        acc[i][0] = (f32x4){0.f, 0.f, 0.f, 0.f};
        acc[i][1] = (f32x4){0.f, 0.f, 0.f, 0.f};
    }

    const bf16x8* __restrict__ Wp = (const bf16x8*)W2g;

    for (int dx = 0; dx < 9; dx++) {
        // A-frags for all 9 dy at this dx, both m-tiles (L2-resident, coalesced 16B/lane)
        bf16x8 Afr[9][2];
        #pragma unroll
        for (int dy = 0; dy < 9; dy++) {
            int tap = dy * 9 + dx;
            Afr[dy][0] = Wp[((0 * 81 + tap) * 4 + quad) * 16 + l15];
            Afr[dy][1] = Wp[((1 * 81 + tap) * 4 + quad) * 16 + l15];
        }
        #pragma unroll
        for (int rp = 0; rp < 16; rp++) {           // lds row (local to wave): out_r = rp - dy
            const int ldsrow = wave * 8 + rp;
            const bf16x8 bfrag =
                *(const bf16x8*)&ldsx[(ldsrow * RCOLS + (l15 + dx)) * CP + quad * 8];
            #pragma unroll
            for (int dy = 0; dy < 9; dy++) {
                const int orr = rp - dy;
                if (orr >= 0 && orr < 8) {
                    acc[orr][0] = __builtin_amdgcn_mfma_f32_16x16x32_bf16(
                        Afr[dy][0], bfrag, acc[orr][0], 0, 0, 0);
                    acc[orr][1] = __builtin_amdgcn_mfma_f32_16x16x32_bf16(
                        Afr[dy][1], bfrag, acc[orr][1], 0, 0, 0);
                }
            }
        }
    }

    // ---- epilogue: D layout col = lane&15 (pixel), row = quad*4 + reg (och within m-tile) ----
    float* outn = out + (size_t)n * NOUT * H * W;
    #pragma unroll
    for (int orr = 0; orr < 8; orr++) {
        const int row = hb * HT + wave * 8 + orr;
        const int col = wb * WTL + l15;
        #pragma unroll
        for (int mt = 0; mt < 2; mt++) {
            #pragma unroll
            for (int reg = 0; reg < 4; reg++) {
                const int och = mt * 16 + quad * 4 + reg;
                outn[(och * H + row) * W + col] = acc[orr][mt][reg] + bias[och];
            }
        }
    }
}

extern "C" void kernel_launch(void* const* d_in, const int* in_sizes, int n_in,
                              void* d_out, int out_size, void* d_ws, size_t ws_size,
                              hipStream_t stream) {
    const float* x    = (const float*)d_in[0];
    const float* wp   = (const float*)d_in[1];   // (32,32,3)
    const float* bias = (const float*)d_in[2];   // (32,)
    float* out = (float*)d_out;
    unsigned short* W2g = (unsigned short*)d_ws; // 165,888 B of scratch

    genw_kernel<<<4, 256, 0, stream>>>(wp, W2g);
    const int blocks = NB * (H / HT) * (W / WTL);   // 16*6*12 = 1152
    conv_kernel<<<blocks, 256, 0, stream>>>(x, W2g, bias, out);
}

// Round 2
// 211.333 us; speedup vs baseline: 1.5299x; 1.5299x over previous
//
#include <hip/hip_runtime.h>

#define H 192
#define W 192
#define CIN 32
#define NOUT 32
#define NB 16
#define PADI 4

#define HT 16          // output rows per block
#define WTL 16         // output cols per block
#define RROWS 24       // HT + 8 halo
#define RCOLS 24       // WTL + 8 halo

typedef __attribute__((ext_vector_type(8))) short bf16x8;
typedef __attribute__((ext_vector_type(4))) float f32x4;

__device__ __forceinline__ unsigned short f2bf(float f) {
    union { float f; unsigned int u; } v; v.f = f;
    unsigned int r = v.u + 0x7fffu + ((v.u >> 16) & 1u);
    return (unsigned short)(r >> 16);
}

// ---- Gaussian kernel generation: one thread per (o, i) pair ----
// Output layout (bf16 as ushort): W2g[mt][tap][quad][m][j]  (mt=o>>4, m=o&15, quad=i>>3, j=i&7)
// so conv-kernel lane l reads A[m=l&15][k=8*(l>>4)+j] as one contiguous 16B vector.
__global__ void genw_kernel(const float* __restrict__ wp, unsigned short* __restrict__ W2g) {
    int idx = blockIdx.x * blockDim.x + threadIdx.x;
    if (idx >= NOUT * CIN) return;
    int o = idx / CIN;
    float sx = wp[idx * 3 + 0], sy = wp[idx * 3 + 1], th = wp[idx * 3 + 2];
    float rad = th / 180.0f * 3.14159265358979323846f;
    float co = cosf(rad), si = sinf(rad);
    float sx2 = sx * sx, sy2 = sy * sy;
    float a = co * co * sx2 + si * si * sy2;
    float b = co * si * (sx2 - sy2);
    float d = si * si * sx2 + co * co * sy2;
    float det = a * d - b * b;
    float ia = d / det, ib = -b / det, idd = a / det;
    float ker[81];
    float sum = 0.0f;
    for (int ky = 0; ky < 9; ky++) {
        float yy = (float)(ky - 4);
        for (int kx = 0; kx < 9; kx++) {
            float xx = (float)(kx - 4);
            float q = ia * xx * xx + 2.0f * ib * xx * yy + idd * yy * yy;
            float v = expf(-0.5f * q);
            ker[ky * 9 + kx] = v;
            sum += v;
        }
    }
    float inv = 1.0f / sum;
    int i = idx % CIN;
    int mt = o >> 4, m = o & 15, quad = i >> 3, j = i & 7;
    for (int tap = 0; tap < 81; tap++) {
        W2g[((((mt * 81 + tap) * 4 + quad) * 16 + m) << 3) + j] = f2bf(ker[tap] * inv);
    }
}

// ---- Conv kernel: implicit GEMM ----
// Block: 256 thr = 4 waves; tile 16 rows x 16 cols, 32 och.
// Wave w: mt = w&1 (16 och), rows [(w>>1)*8, +8) of the tile.
// LDS x-tile layout: [quad][r][w][8ch] (16B granules, lane-linear => ~conflict-free).
// dx-outer tap loop: one B-frag (8ch x 16px) feeds up to 8 dy MFMAs (cross-row reuse).
__global__ __launch_bounds__(256, 4) void conv_kernel(
    const float* __restrict__ x, const unsigned short* __restrict__ W2g,
    const float* __restrict__ bias, float* __restrict__ out)
{
    __shared__ __align__(16) unsigned short ldsx[4 * RROWS * RCOLS * 8];  // 36,864 B

    const int t = threadIdx.x;
    const int bid = blockIdx.x;
    const int wb = bid % (W / WTL);                 // 0..11
    const int hb = (bid / (W / WTL)) % (H / HT);    // 0..11
    const int n  = bid / ((W / WTL) * (H / HT));    // 0..15
    const int row0 = hb * HT - PADI;
    const int col0 = wb * WTL - PADI;
    const float* xn = x + (size_t)n * CIN * H * W;

    // ---- stage x tile -> LDS bf16 ----
    // Each thread: one (quad, r, w) granule = 8 channels -> pack -> ds_write_b128.
    // idx is lane-linear => LDS writes conflict-free; global loads coalesce across w.
    #pragma unroll
    for (int it = 0; it < (4 * RROWS * RCOLS) / 256; ++it) {   // 9 iters
        int idx = it * 256 + t;
        int w = idx % RCOLS;
        int r = (idx / RCOLS) % RROWS;
        int quad = idx / (RCOLS * RROWS);
        int row = row0 + r, col = col0 + w;
        unsigned int d[4] = {0u, 0u, 0u, 0u};
        if ((unsigned)row < (unsigned)H && (unsigned)col < (unsigned)W) {
            const float* p = xn + ((size_t)(quad * 8) * H + row) * W + col;
            #pragma unroll
            for (int k = 0; k < 4; k++) {
                float v0 = p[(size_t)(2 * k) * H * W];
                float v1 = p[(size_t)(2 * k + 1) * H * W];
                d[k] = (unsigned int)f2bf(v0) | ((unsigned int)f2bf(v1) << 16);
            }
        }
        *(uint4*)&ldsx[(size_t)idx * 8] = make_uint4(d[0], d[1], d[2], d[3]);
    }
    __syncthreads();

    const int wave = t >> 6;
    const int lane = t & 63;
    const int l15 = lane & 15;      // A: m-row / B: pixel col / D: col
    const int quad4 = lane >> 4;    // A/B: k-group (8 ch) / D: och-quad
    const int mt = wave & 1;        // och tile (16 och)
    const int rbase = (wave >> 1) * 8;  // output-row base within tile

    f32x4 acc[8];
    #pragma unroll
    for (int i = 0; i < 8; i++) acc[i] = (f32x4){0.f, 0.f, 0.f, 0.f};

    const bf16x8* __restrict__ Wp = (const bf16x8*)W2g;

    for (int dx = 0; dx < 9; dx++) {
        bf16x8 Afr[9];
        #pragma unroll
        for (int dy = 0; dy < 9; dy++) {
            int tap = dy * 9 + dx;
            Afr[dy] = Wp[((mt * 81 + tap) * 4 + quad4) * 16 + l15];
        }
        #pragma unroll
        for (int rr = 0; rr < 16; rr++) {           // lds row rel to rbase; out_r = rr - dy
            const int ldsrow = rbase + rr;
            const bf16x8 bfrag =
                *(const bf16x8*)&ldsx[(size_t)(((quad4 * RROWS + ldsrow) * RCOLS) + (l15 + dx)) * 8];
            #pragma unroll
            for (int dy = 0; dy < 9; dy++) {
                const int orr = rr - dy;
                if (orr >= 0 && orr < 8) {
                    acc[orr] = __builtin_amdgcn_mfma_f32_16x16x32_bf16(
                        Afr[dy], bfrag, acc[orr], 0, 0, 0);
                }
            }
        }
    }

    // ---- epilogue: D layout col = lane&15 (pixel), row = quad4*4 + reg (och in m-tile) ----
    float* outn = out + (size_t)n * NOUT * H * W;
    float bb[4];
    #pragma unroll
    for (int reg = 0; reg < 4; reg++) bb[reg] = bias[mt * 16 + quad4 * 4 + reg];
    #pragma unroll
    for (int orr = 0; orr < 8; orr++) {
        const int row = hb * HT + rbase + orr;
        const int col = wb * WTL + l15;
        #pragma unroll
        for (int reg = 0; reg < 4; reg++) {
            const int och = mt * 16 + quad4 * 4 + reg;
            outn[((size_t)och * H + row) * W + col] = acc[orr][reg] + bb[reg];
        }
    }
}

extern "C" void kernel_launch(void* const* d_in, const int* in_sizes, int n_in,
                              void* d_out, int out_size, void* d_ws, size_t ws_size,
                              hipStream_t stream) {
    const float* x    = (const float*)d_in[0];
    const float* wp   = (const float*)d_in[1];   // (32,32,3)
    const float* bias = (const float*)d_in[2];   // (32,)
    float* out = (float*)d_out;
    unsigned short* W2g = (unsigned short*)d_ws; // 165,888 B of scratch

    genw_kernel<<<4, 256, 0, stream>>>(wp, W2g);
    const int blocks = NB * (H / HT) * (W / WTL);   // 16*12*12 = 2304
    conv_kernel<<<blocks, 256, 0, stream>>>(x, W2g, bias, out);
}

// Round 3
// 190.202 us; speedup vs baseline: 1.6998x; 1.1111x over previous
//
#include <hip/hip_runtime.h>

#define H 192
#define W 192
#define CIN 32
#define NOUT 32
#define NB 16
#define PADI 4

#define HT 16          // output rows per block
#define WTL 16         // output cols per block
#define RROWS 24       // HT + 8 halo
#define RCOLS 24       // WTL + 8 halo

typedef __attribute__((ext_vector_type(8))) short bf16x8;
typedef __attribute__((ext_vector_type(4))) float f32x4;

__device__ __forceinline__ unsigned short f2bf(float f) {
    union { float f; unsigned int u; } v; v.f = f;
    unsigned int r = v.u + 0x7fffu + ((v.u >> 16) & 1u);
    return (unsigned short)(r >> 16);
}

// ---- Gaussian kernel generation: one block per (o,i) pair, one thread per tap ----
// 1024 blocks x 128 threads: taps 0..80 active; shfl+LDS reduce for the normalizer.
// Output layout (bf16 as ushort): W2g[mt][tap][quad][m][j]  (mt=o>>4, m=o&15, quad=i>>3, j=i&7)
__global__ void genw_kernel(const float* __restrict__ wp, unsigned short* __restrict__ W2g) {
    const int b = blockIdx.x;          // = o*32 + i
    const int o = b >> 5;
    const int i = b & 31;
    const int t = threadIdx.x;         // 0..127

    float sx = wp[b * 3 + 0], sy = wp[b * 3 + 1], th = wp[b * 3 + 2];
    float rad = th / 180.0f * 3.14159265358979323846f;
    float co = cosf(rad), si = sinf(rad);
    float sx2 = sx * sx, sy2 = sy * sy;
    float a = co * co * sx2 + si * si * sy2;
    float bb = co * si * (sx2 - sy2);
    float d = si * si * sx2 + co * co * sy2;
    float det = a * d - bb * bb;
    float ia = d / det, ib = -bb / det, idd = a / det;

    const int tap = t;
    float e = 0.0f;
    if (tap < 81) {
        float xx = (float)(tap % 9 - 4);
        float yy = (float)(tap / 9 - 4);
        float q = ia * xx * xx + 2.0f * ib * xx * yy + idd * yy * yy;
        e = expf(-0.5f * q);
    }
    // reduce across 128 threads (2 waves)
    float s = e;
    #pragma unroll
    for (int off = 32; off > 0; off >>= 1) s += __shfl_down(s, off);
    __shared__ float ws[2];
    if ((t & 63) == 0) ws[t >> 6] = s;
    __syncthreads();
    float total = ws[0] + ws[1];

    if (tap < 81) {
        int mt = o >> 4, m = o & 15, quad = i >> 3, j = i & 7;
        W2g[((((mt * 81 + tap) * 4 + quad) * 16 + m) << 3) + j] = f2bf(e / total);
    }
}

// ---- Conv kernel: implicit GEMM ----
// Block: 256 thr = 4 waves; tile 16 rows x 16 cols, 32 och.
// Wave w: mt = w&1 (16 och), rows [(w>>1)*8, +8) of the tile.
// LDS x-tile layout: [quad][r][w][8ch] (16B granules, lane-linear => conflict-free).
// dx-outer tap loop, fully unrolled, with A-frag double-buffer prefetch (dx+1 loads
// issued before dx's MFMAs). Staging: all 72 fp32 loads in flight, then pack+write.
__global__ __launch_bounds__(256, 4) void conv_kernel(
    const float* __restrict__ x, const unsigned short* __restrict__ W2g,
    const float* __restrict__ bias, float* __restrict__ out)
{
    __shared__ __align__(16) unsigned short ldsx[4 * RROWS * RCOLS * 8];  // 36,864 B

    const int t = threadIdx.x;
    // XCD-contiguous swizzle: 8 classes x 288 tiles (= 2 whole images per class)
    const int bid = (blockIdx.x & 7) * 288 + (blockIdx.x >> 3);
    const int wb = bid % (W / WTL);                 // 0..11
    const int hb = (bid / (W / WTL)) % (H / HT);    // 0..11
    const int n  = bid / ((W / WTL) * (H / HT));    // 0..15
    const int row0 = hb * HT - PADI;
    const int col0 = wb * WTL - PADI;
    const float* xn = x + (size_t)n * CIN * H * W;

    // ---- phase 1: issue ALL staging loads (72 fp32 in VGPRs) ----
    float v[9][8];
    #pragma unroll
    for (int it = 0; it < 9; ++it) {
        int idx = it * 256 + t;
        int w = idx % RCOLS;
        int r = (idx / RCOLS) % RROWS;
        int quad = idx / (RCOLS * RROWS);
        int row = row0 + r, col = col0 + w;
        #pragma unroll
        for (int k = 0; k < 8; k++) v[it][k] = 0.0f;
        if ((unsigned)row < (unsigned)H && (unsigned)col < (unsigned)W) {
            const float* p = xn + ((size_t)(quad * 8) * H + row) * W + col;
            #pragma unroll
            for (int k = 0; k < 8; k++) v[it][k] = p[(size_t)k * H * W];
        }
    }
    // ---- phase 2: pack + LDS write (lane-linear b128, conflict-free) ----
    #pragma unroll
    for (int it = 0; it < 9; ++it) {
        int idx = it * 256 + t;
        unsigned int d[4];
        #pragma unroll
        for (int k = 0; k < 4; k++)
            d[k] = (unsigned int)f2bf(v[it][2 * k]) | ((unsigned int)f2bf(v[it][2 * k + 1]) << 16);
        *(uint4*)&ldsx[(size_t)idx * 8] = make_uint4(d[0], d[1], d[2], d[3]);
    }

    const int wave = t >> 6;
    const int lane = t & 63;
    const int l15 = lane & 15;      // A: m-row / B: pixel col / D: col
    const int quad4 = lane >> 4;    // A/B: k-group (8 ch) / D: och-quad
    const int mt = wave & 1;        // och tile (16 och)
    const int rbase = (wave >> 1) * 8;  // output-row base within tile

    const bf16x8* __restrict__ Wp = (const bf16x8*)W2g;

    // preload A-frags for dx=0 (latency hidden under the barrier)
    bf16x8 A[2][9];
    #pragma unroll
    for (int dy = 0; dy < 9; dy++)
        A[0][dy] = Wp[((mt * 81 + dy * 9 + 0) * 4 + quad4) * 16 + l15];

    __syncthreads();

    f32x4 acc[8];
    #pragma unroll
    for (int i = 0; i < 8; i++) acc[i] = (f32x4){0.f, 0.f, 0.f, 0.f};

    const unsigned short* bptr = &ldsx[(size_t)(((quad4 * RROWS + rbase) * RCOLS) + l15) * 8];

    #pragma unroll
    for (int dx = 0; dx < 9; dx++) {
        const int cur = dx & 1, nxt = cur ^ 1;
        if (dx < 8) {
            #pragma unroll
            for (int dy = 0; dy < 9; dy++)
                A[nxt][dy] = Wp[((mt * 81 + dy * 9 + (dx + 1)) * 4 + quad4) * 16 + l15];
        }
        #pragma unroll
        for (int rr = 0; rr < 16; rr++) {           // lds row rel to rbase; out_r = rr - dy
            const bf16x8 bfrag = *(const bf16x8*)&bptr[(size_t)(rr * RCOLS + dx) * 8];
            #pragma unroll
            for (int dy = 0; dy < 9; dy++) {
                const int orr = rr - dy;
                if (orr >= 0 && orr < 8) {
                    acc[orr] = __builtin_amdgcn_mfma_f32_16x16x32_bf16(
                        A[cur][dy], bfrag, acc[orr], 0, 0, 0);
                }
            }
        }
    }

    // ---- epilogue: D layout col = lane&15 (pixel), row = quad4*4 + reg (och in m-tile) ----
    float* outn = out + (size_t)n * NOUT * H * W;
    float bb[4];
    #pragma unroll
    for (int reg = 0; reg < 4; reg++) bb[reg] = bias[mt * 16 + quad4 * 4 + reg];
    #pragma unroll
    for (int orr = 0; orr < 8; orr++) {
        const int row = hb * HT + rbase + orr;
        const int col = wb * WTL + l15;
        #pragma unroll
        for (int reg = 0; reg < 4; reg++) {
            const int och = mt * 16 + quad4 * 4 + reg;
            outn[((size_t)och * H + row) * W + col] = acc[orr][reg] + bb[reg];
        }
    }
}

extern "C" void kernel_launch(void* const* d_in, const int* in_sizes, int n_in,
                              void* d_out, int out_size, void* d_ws, size_t ws_size,
                              hipStream_t stream) {
    const float* x    = (const float*)d_in[0];
    const float* wp   = (const float*)d_in[1];   // (32,32,3)
    const float* bias = (const float*)d_in[2];   // (32,)
    float* out = (float*)d_out;
    unsigned short* W2g = (unsigned short*)d_ws; // 165,888 B of scratch

    genw_kernel<<<NOUT * CIN, 128, 0, stream>>>(wp, W2g);
    const int blocks = NB * (H / HT) * (W / WTL);   // 16*12*12 = 2304
    conv_kernel<<<blocks, 256, 0, stream>>>(x, W2g, bias, out);
}